// Round 3
// baseline (431.174 us; speedup 1.0000x reference)
//
#include <hip/hip_runtime.h>
#include <hip/hip_bf16.h>
#include <stdint.h>

#define B_   2048
#define P_   20
#define D_   64
#define V_   100000
#define T_   33
#define FIN  2240          // 35*64
#define KE   2112          // 33*64  (emb-only K; raw cols folded into epilogue)
#define M_   (B_*P_)       // 40960
#define H1_  512
#define H2_  256
#define NKT  33            // K-tiles of 64

using bf16 = __hip_bfloat16;
typedef __bf16 bf16x8 __attribute__((ext_vector_type(8)));
typedef float  f32x4  __attribute__((ext_vector_type(4)));

__device__ __forceinline__ void gload16(const void* g, void* l) {
    __builtin_amdgcn_global_load_lds(
        (const __attribute__((address_space(1))) uint32_t*)g,
        (__attribute__((address_space(3))) uint32_t*)l, 16, 0, 0);
}

// ---------------------------------------------------------------------------
// prep 1: column sums of W1 rows 0..63 (S0) and 64..127 (S1).  S01 = [S0|S1]
// coalesced: thread -> (s, n); k-loop strided, unrolled for ILP.
// ---------------------------------------------------------------------------
__global__ __launch_bounds__(256) void colsum_k(
    const float* __restrict__ W1, float* __restrict__ S01)
{
    int g = blockIdx.x * 256 + threadIdx.x;   // 0..1023
    int s = g >> 9, n = g & 511;
    const float* p = W1 + (size_t)(s * 64) * H1_ + n;
    float acc = 0.f;
    #pragma unroll 8
    for (int k = 0; k < 64; ++k) acc += p[(size_t)k * H1_];
    S01[s * H1_ + n] = acc;
}

// ---------------------------------------------------------------------------
// prep 2: W1 rows 128.. -> W1t (512 x 2112) bf16 row-major (transposed)
// ---------------------------------------------------------------------------
__global__ __launch_bounds__(256) void w1t_k(
    const float* __restrict__ W1, bf16* __restrict__ W1t)
{
    int idx = blockIdx.x * 256 + threadIdx.x;   // n*KE + k
    int n = idx / KE;
    int k = idx - n * KE;
    W1t[idx] = __float2bfloat16(W1[(size_t)(k + 128) * H1_ + n]);
}

// ---------------------------------------------------------------------------
// prep 3: generic W (K x N fp32) -> Wt (N x K bf16)
// ---------------------------------------------------------------------------
__global__ __launch_bounds__(256) void transpose_bf16_k(
    const float* __restrict__ W, bf16* __restrict__ Wt, int K, int N)
{
    int idx = blockIdx.x * 256 + threadIdx.x;
    if (idx >= N * K) return;
    int n = idx / K;
    int k = idx - n * K;
    Wt[idx] = __float2bfloat16(W[(size_t)k * N + n]);
}

// ---------------------------------------------------------------------------
// FUSED gather + GEMM1:  h1 = relu(feat @ W1 + b1)
//   grid 256 (BM=160, 1 block/CU), 512 thr = 8 waves (2x4), wave 80x128.
//   A: emb rows gathered fp32 DIRECT to LDS via global_load_lds (no VGPR
//      round-trip), double-buffered 2x40KB, XOR-swizzled via pre-swizzled
//      per-lane SOURCE address (rule #21).  BK=64 = one emb t-block.
//   B: W1t bf16 via global_load_lds, single 64KB buffer, pre-swizzled src.
//   Pipeline: raw s_barrier + counted s_waitcnt vmcnt(10) — never drains
//      the gather in the main loop (T3/T4).  18 vmem/wave/iter uniform
//      (8 B + 5 A + 5 idx), tails clamped to keep counts uniform.
//   Raw feature cols (rank-2) folded into epilogue via S0/S1.
// ---------------------------------------------------------------------------
__global__ __launch_bounds__(512, 2) void fused_gemm1_k(
    const float* __restrict__ x_raw, const int* __restrict__ x_idx,
    const float* __restrict__ emb, const bf16* __restrict__ W1t,
    const float* __restrict__ b1, const float* __restrict__ S01,
    bf16* __restrict__ h1)
{
    extern __shared__ char smem[];
    char* Als = smem;               // 2 x [160][64] fp32 swizzled = 2 x 40960
    char* Bls = smem + 81920;       // [512][64] bf16 swizzled = 65536

    const int tid = threadIdx.x;
    const int w = tid >> 6, l = tid & 63;
    const int wr = w >> 2, wc = w & 3;          // 2 x 4 wave grid
    const int fr = l & 15, fq = l >> 4;
    const int m0 = blockIdx.x * 160;

    const int l4  = l >> 4;                     // 0..3  (A-staging row-in-group)
    const int l15 = l & 15;                     // A-staging 16B unit
    const int bn  = w * 8 + (l >> 3);           // B-staging row-in-64-group
    const int bcolb = 16 * ((l & 7) ^ (l >> 3));// B-staging pre-swizzled col byte

    f32x4 acc[5][8] = {};
    int ivA[5], ivB[5];

    auto load_idx = [&](int t, int (&iv)[5]) {
        #pragma unroll
        for (int p = 0; p < 5; ++p)
            iv[p] = x_idx[(size_t)(m0 + w * 20 + p * 4 + l4) * T_ + t];
    };
    auto issue_A = [&](int t, int buf, int (&iv)[5]) {
        char* base = Als + buf * 40960 + (w * 20) * 256;
        #pragma unroll
        for (int p = 0; p < 5; ++p) {
            int r7   = (w * 20 + p * 4 + l4) & 7;
            int scol = (16 * l15) ^ (r7 << 4);      // pre-swizzled source col
            const char* src = (const char*)(emb + ((size_t)t * V_ + (size_t)iv[p]) * D_) + scol;
            gload16(src, base + p * 1024);
        }
    };
    auto issue_B = [&](int kt) {
        char* base = Bls + w * 1024;
        #pragma unroll
        for (int q = 0; q < 8; ++q)
            gload16((const char*)(W1t + (size_t)(q * 64 + bn) * KE + kt * 64) + bcolb,
                    base + q * 8192);
    };

    auto body = [&](int kt, int (&ivUse)[5], int (&ivLoad)[5], bool tail) {
        issue_B(kt);                                          // +8
        if (!tail) {
            int tn = kt + 1 < NKT ? kt + 1 : NKT - 1;
            int tl = kt + 2 < NKT ? kt + 2 : NKT - 1;
            issue_A(tn, (kt + 1) & 1, ivUse);                 // +5
            load_idx(tl, ivLoad);                             // +5
            // wait A(kt) + B(kt); leave A(kt+1)+idx (10) in flight
            asm volatile("s_waitcnt vmcnt(10)" ::: "memory");
        } else {
            asm volatile("s_waitcnt vmcnt(0)" ::: "memory");
        }
        __builtin_amdgcn_s_barrier();
        __builtin_amdgcn_sched_barrier(0);

        const char* Ab = Als + (kt & 1) * 40960;
        #pragma unroll
        for (int kk = 0; kk < 2; ++kk) {
            bf16x8 af[5];
            #pragma unroll
            for (int i = 0; i < 5; ++i) {
                int r  = wr * 80 + i * 16 + fr;
                int xr = (r & 7) << 4;
                int b0 = r * 256 + ((kk * 128 + fq * 32) ^ xr);
                int b1b = r * 256 + ((kk * 128 + fq * 32 + 16) ^ xr);
                float4 a0 = *(const float4*)(Ab + b0);
                float4 a1 = *(const float4*)(Ab + b1b);
                bf16x8 t;
                t[0] = (__bf16)a0.x; t[1] = (__bf16)a0.y;
                t[2] = (__bf16)a0.z; t[3] = (__bf16)a0.w;
                t[4] = (__bf16)a1.x; t[5] = (__bf16)a1.y;
                t[6] = (__bf16)a1.z; t[7] = (__bf16)a1.w;
                af[i] = t;
            }
            #pragma unroll
            for (int j = 0; j < 8; ++j) {
                int n    = wc * 128 + j * 16 + fr;
                int byte = (n * 128 + kk * 64 + fq * 16) ^ ((n & 7) << 4);
                bf16x8 bg = *(const bf16x8*)(Bls + byte);
                #pragma unroll
                for (int i = 0; i < 5; ++i)
                    acc[i][j] = __builtin_amdgcn_mfma_f32_16x16x32_bf16(
                        af[i], bg, acc[i][j], 0, 0, 0);
            }
        }
        __builtin_amdgcn_s_barrier();   // all LDS reads consumed (by MFMA) before next writes
    };

    // prologue: idx(0) -> ivA (compiler-waited), A(0) -> buf0, idx(1) -> ivB
    load_idx(0, ivA);
    issue_A(0, 0, ivA);
    load_idx(1, ivB);

    for (int kt = 0; kt < NKT - 1; kt += 2) {
        body(kt,     ivB, ivA, false);
        body(kt + 1, ivA, ivB, false);
    }
    body(NKT - 1, ivB, ivA, true);      // kt=32: no new issues, full drain

    // epilogue: bias + rank-2 raw contribution + relu -> h1 (bf16)
    const float* S0 = S01;
    const float* S1 = S01 + H1_;
    #pragma unroll
    for (int i = 0; i < 5; ++i) {
        int rbase = wr * 80 + i * 16 + fq * 4;
        float x0[4], x1[4];
        #pragma unroll
        for (int r2 = 0; r2 < 4; ++r2) {
            int m = m0 + rbase + r2;
            x0[r2] = x_raw[2 * m];
            x1[r2] = x_raw[2 * m + 1];
        }
        #pragma unroll
        for (int j = 0; j < 8; ++j) {
            int n = wc * 128 + j * 16 + fr;
            float bb = b1[n], s0 = S0[n], s1 = S1[n];
            #pragma unroll
            for (int r2 = 0; r2 < 4; ++r2) {
                float v = acc[i][j][r2] + bb + x0[r2] * s0 + x1[r2] * s1;
                h1[(size_t)(m0 + rbase + r2) * H1_ + n] =
                    __float2bfloat16(fmaxf(v, 0.0f));
            }
        }
    }
}

// ---------------------------------------------------------------------------
// FUSED GEMM2 + head:  h2 = relu(h1 @ W2 + b2); logits = h2 @ W3 + b3;
// softmax over P=20.  BM=160 (=8 batches), BN=256 (full) -> logits+softmax
// computed in-block; h2 never touches HBM.  grid 256, 8 waves (2x4),
// wave tile 80x64, acc 5x4.  Simple 2-barrier K-loop (8 tiles of BK=64).
// ---------------------------------------------------------------------------
__global__ __launch_bounds__(512) void gemm2_head_k(
    const bf16* __restrict__ h1, const bf16* __restrict__ W2t,
    const float* __restrict__ b2, const float* __restrict__ W3,
    const float* __restrict__ b3, float* __restrict__ out)
{
    __shared__ char  As[20480];       // [160][64] bf16 swizzled
    __shared__ char  Bs[32768];       // [256][64] bf16 swizzled
    __shared__ float w3s[H2_];
    __shared__ float b2s[H2_];
    __shared__ float logq[4][160];
    __shared__ float logits[160];

    const int tid = threadIdx.x;
    const int w = tid >> 6, l = tid & 63;
    const int wr = w >> 2, wc = w & 3;
    const int fr = l & 15, fq = l >> 4;
    const int m0 = blockIdx.x * 160;
    const int r8 = l >> 3, c8 = l & 7;

    if (tid < H2_) { w3s[tid] = W3[tid]; b2s[tid] = b2[tid]; }

    f32x4 acc[5][4] = {};

    for (int kt = 0; kt < 8; ++kt) {
        // A: 20 x 1KB instrs (8 rows each), waves round-robin
        for (int s = w; s < 20; s += 8) {
            int row = s * 8 + r8;
            const char* src = (const char*)(h1 + (size_t)(m0 + row) * H1_ + kt * 64)
                              + ((16 * c8) ^ ((row & 7) << 4));
            gload16(src, As + s * 1024);
        }
        // B: 32 x 1KB instrs, 4 per wave
        #pragma unroll
        for (int q = 0; q < 4; ++q) {
            int s = q * 8 + w;
            int row = s * 8 + r8;
            const char* src = (const char*)(W2t + (size_t)row * H1_ + kt * 64)
                              + ((16 * c8) ^ ((row & 7) << 4));
            gload16(src, Bs + s * 1024);
        }
        __syncthreads();

        #pragma unroll
        for (int kk = 0; kk < 2; ++kk) {
            bf16x8 af[5];
            #pragma unroll
            for (int i = 0; i < 5; ++i) {
                int r = wr * 80 + i * 16 + fr;
                int byte = (r * 128 + kk * 64 + fq * 16) ^ ((r & 7) << 4);
                af[i] = *(const bf16x8*)(As + byte);
            }
            #pragma unroll
            for (int j = 0; j < 4; ++j) {
                int n = wc * 64 + j * 16 + fr;
                int byte = (n * 128 + kk * 64 + fq * 16) ^ ((n & 7) << 4);
                bf16x8 bg = *(const bf16x8*)(Bs + byte);
                #pragma unroll
                for (int i = 0; i < 5; ++i)
                    acc[i][j] = __builtin_amdgcn_mfma_f32_16x16x32_bf16(
                        af[i], bg, acc[i][j], 0, 0, 0);
            }
        }
        __syncthreads();
    }

    // head: per-lane partial logits, reduce over fr, cross-wave via LDS
    #pragma unroll
    for (int i = 0; i < 5; ++i) {
        #pragma unroll
        for (int r2 = 0; r2 < 4; ++r2) {
            float s = 0.f;
            #pragma unroll
            for (int j = 0; j < 4; ++j) {
                int col = wc * 64 + j * 16 + fr;
                float v = fmaxf(acc[i][j][r2] + b2s[col], 0.f);
                s += v * w3s[col];
            }
            #pragma unroll
            for (int off = 1; off < 16; off <<= 1) s += __shfl_xor(s, off);
            if (fr == 0)
                logq[wc][wr * 80 + i * 16 + fq * 4 + r2] = s;
        }
    }
    __syncthreads();
    if (tid < 160)
        logits[tid] = logq[0][tid] + logq[1][tid] + logq[2][tid] + logq[3][tid] + b3[0];
    __syncthreads();
    if (tid < 160) {
        int bb = (tid / 20) * 20;
        float mx = -1e30f;
        #pragma unroll
        for (int p = 0; p < 20; ++p) mx = fmaxf(mx, logits[bb + p]);
        float sum = 0.f;
        #pragma unroll
        for (int p = 0; p < 20; ++p) sum += expf(logits[bb + p] - mx);
        out[m0 + tid] = expf(logits[tid] - mx) / sum;
    }
}

// ---------------------------------------------------------------------------
extern "C" void kernel_launch(void* const* d_in, const int* in_sizes, int n_in,
                              void* d_out, int out_size, void* d_ws, size_t ws_size,
                              hipStream_t stream)
{
    const float* x_raw = (const float*)d_in[0];
    const int*   x_idx = (const int*)  d_in[1];
    const float* emb   = (const float*)d_in[2];
    const float* W1    = (const float*)d_in[3];
    const float* b1    = (const float*)d_in[4];
    const float* W2    = (const float*)d_in[5];
    const float* b2    = (const float*)d_in[6];
    const float* W3    = (const float*)d_in[7];
    const float* b3    = (const float*)d_in[8];

    char* ws = (char*)d_ws;
    size_t off = 0;
    bf16*  W1t = (bf16*) (ws + off); off += (size_t)H1_ * KE * 2;    // 2.16 MB
    bf16*  W2t = (bf16*) (ws + off); off += (size_t)H2_ * H1_ * 2;   // 0.26 MB
    float* S01 = (float*)(ws + off); off += (size_t)2 * H1_ * 4;     // 4 KB
    bf16*  h1  = (bf16*) (ws + off); off += (size_t)M_ * H1_ * 2;    // 42 MB

    // prep
    colsum_k<<<4, 256, 0, stream>>>(W1, S01);
    w1t_k<<<(H1_ * KE) / 256, 256, 0, stream>>>(W1, W1t);
    transpose_bf16_k<<<(H2_ * H1_ + 255) / 256, 256, 0, stream>>>(W2, W2t, H1_, H2_);

    // fused gather + GEMM1 (144 KB dynamic LDS)
    hipFuncSetAttribute((const void*)fused_gemm1_k,
                        hipFuncAttributeMaxDynamicSharedMemorySize, 147456);
    fused_gemm1_k<<<256, 512, 147456, stream>>>(x_raw, x_idx, emb, W1t, b1, S01, h1);

    // fused GEMM2 + head -> softmax out
    gemm2_head_k<<<256, 512, 0, stream>>>(h1, W2t, b2, W3, b3, (float*)d_out);
}